// Round 1
// 456.756 us; speedup vs baseline: 1.1061x; 1.1061x over previous
//
#include <hip/hip_runtime.h>

// Problem: B=16, C=1, H=2048, W=2048 fp32.
// out = a0*x + a1*(left+right) + a2*(up+down)   (replicate-padded 5-pt stencil)
//     + w0 + w1*x + w2*x^2 + w3*x^3             (Horner, CONST=0)
//
// Memory-bound. v2 strategy:
//  - 8 rows per thread, rolling (up,cur,dn) float4 window: each interior row
//    loaded once; read amplification 1.25x intrinsic (was ~1.5x observed).
//  - Horizontal neighbors via __shfl from adjacent lanes (kills the two
//    stride-16B gather loads per wave-row; lanes 0/63 use a 1-lane predicated
//    scalar load).
//  - XCD-aware block swizzle: contiguous row-bands per XCD so band-boundary
//    re-reads hit the local (non-coherent) L2.
//  - Non-temporal stores: output is never re-read; don't evict reusable rows.

#define H_DIM 2048
#define W_DIM 2048
#define W4    (W_DIM / 4)   // 512 float4 per row
#define RPT   8             // rows per thread
#define BLK   256           // threads per block -> 256 float4 columns = half row

typedef float fvec4 __attribute__((ext_vector_type(4)));

__global__ __launch_bounds__(BLK) void FCNN_63651415326860_kernel(
    const float* __restrict__ x,
    const float* __restrict__ a,
    const float* __restrict__ w,
    float* __restrict__ out)
{
    // ---- XCD-aware swizzle (bijective: gridDim.x = 8192, divisible by 8) ----
    // Hardware round-robins blockIdx.x across the 8 XCDs; remap so each XCD
    // gets a contiguous chunk of logical blocks = a contiguous band of rows.
    const int chunk = gridDim.x >> 3;
    const int swz   = (blockIdx.x & 7) * chunk + (blockIdx.x >> 3);

    const int half = swz & 1;     // which half-row (0: cols 0..255, 1: 256..511)
    const int band = swz >> 1;    // 8-row band index across B*H

    const int col4 = half * BLK + (int)threadIdx.x;   // float4 column, 0..511
    const int lane = threadIdx.x & 63;

    const int rowg0 = band * RPT;              // first global row of this band
    const int row0  = rowg0 & (H_DIM - 1);     // row within image (RPT | H_DIM,
                                               // so a band never crosses images)

    const float4* __restrict__ x4 = (const float4*)x;

    // broadcast scalars (uniform addresses -> s_load, cached)
    const float a0 = a[0], a1 = a[1], a2 = a[2];
    const float w0 = w[0], w1 = w[1], w2 = w[2], w3 = w[3];

    int v = rowg0 * W4 + col4;                 // float4 index (max 16.7M, fits int)

    // rolling window
    float4 cur = x4[v];
    float4 up  = (row0 == 0) ? cur : x4[v - W4];

    #pragma unroll
    for (int r = 0; r < RPT; ++r) {
        const int row = row0 + r;
        const float4 dn = (row == H_DIM - 1) ? cur : x4[v + W4];

        // horizontal neighbors: adjacent lane's register via shuffle
        float lw = __shfl(cur.w, (lane > 0)  ? lane - 1 : 0);
        float rw = __shfl(cur.x, (lane < 63) ? lane + 1 : 63);
        // wave-edge lanes: 1-active-lane predicated loads (L1/L2 hit)
        if (lane == 0)
            lw = (col4 == 0)      ? cur.x : x[(size_t)v * 4 - 1];
        if (lane == 63)
            rw = (col4 == W4 - 1) ? cur.w : x[(size_t)v * 4 + 4];

        fvec4 res;
        res.x = a0 * cur.x + a1 * (lw    + cur.y) + a2 * (up.x + dn.x)
              + fmaf(fmaf(fmaf(w3, cur.x, w2), cur.x, w1), cur.x, w0);
        res.y = a0 * cur.y + a1 * (cur.x + cur.z) + a2 * (up.y + dn.y)
              + fmaf(fmaf(fmaf(w3, cur.y, w2), cur.y, w1), cur.y, w0);
        res.z = a0 * cur.z + a1 * (cur.y + cur.w) + a2 * (up.z + dn.z)
              + fmaf(fmaf(fmaf(w3, cur.z, w2), cur.z, w1), cur.z, w0);
        res.w = a0 * cur.w + a1 * (cur.z + rw   ) + a2 * (up.w + dn.w)
              + fmaf(fmaf(fmaf(w3, cur.w, w2), cur.w, w1), cur.w, w0);

        // output never re-read: bypass cache retention
        __builtin_nontemporal_store(res, (fvec4*)(out + (size_t)v * 4));

        up = cur;
        cur = dn;
        v += W4;
    }
}

extern "C" void kernel_launch(void* const* d_in, const int* in_sizes, int n_in,
                              void* d_out, int out_size, void* d_ws, size_t ws_size,
                              hipStream_t stream) {
    const float* x = (const float*)d_in[0];   // 16*1*2048*2048 fp32
    const float* a = (const float*)d_in[1];   // 3 fp32
    const float* w = (const float*)d_in[2];   // 4 fp32
    float* out = (float*)d_out;

    const int total4 = out_size / 4;          // 16,777,216 float4s
    const int grid = total4 / (BLK * RPT);    // 8192 blocks

    FCNN_63651415326860_kernel<<<grid, BLK, 0, stream>>>(x, a, w, out);
}

// Round 2
// 449.280 us; speedup vs baseline: 1.1245x; 1.0166x over previous
//
#include <hip/hip_runtime.h>

// Problem: B=16, C=1, H=2048, W=2048 fp32.
// out = a0*x + a1*(left+right) + a2*(up+down)   (replicate-padded 5-pt stencil)
//     + w0 + w1*x + w2*x^2 + w3*x^3             (Horner, CONST=0)
//
// v3 strategy (v2 was latency-bound: VGPR=20 proved only ONE load in flight
// per thread — the rolling up/cur/dn window serialized loads):
//  - Load the full 10-row window (up0, rows 0..7, dn7) as INDEPENDENT
//    upfront global_load_dwordx4 into a statically-indexed register array:
//    10x memory-level parallelism per thread, latency amortized once.
//  - Horizontal neighbors via __shfl of adjacent lanes (edge lanes patch
//    with a 1-active-lane scalar load).
//  - XCD-aware bijective block swizzle: contiguous row-bands per XCD L2.
//  - Non-temporal stores: output never re-read; keep input resident in L3.

#define H_DIM 2048
#define W_DIM 2048
#define W4    (W_DIM / 4)   // 512 float4 per row
#define RPT   8             // rows per thread
#define BLK   256           // threads per block -> 256 float4 cols = half row

typedef float fvec4 __attribute__((ext_vector_type(4)));

__global__ __launch_bounds__(BLK) void FCNN_63651415326860_kernel(
    const float* __restrict__ x,
    const float* __restrict__ a,
    const float* __restrict__ w,
    float* __restrict__ out)
{
    // ---- XCD-aware swizzle (bijective: gridDim.x = 8192, divisible by 8) ----
    const int chunk = gridDim.x >> 3;
    const int swz   = (blockIdx.x & 7) * chunk + (blockIdx.x >> 3);

    const int half = swz & 1;     // which half-row (0: cols 0..255, 1: 256..511)
    const int band = swz >> 1;    // 8-row band index across B*H

    const int col4 = half * BLK + (int)threadIdx.x;   // float4 column, 0..511
    const int lane = threadIdx.x & 63;

    const int rowg0 = band * RPT;              // first global row of this band
    const int row0  = rowg0 & (H_DIM - 1);     // row within image (RPT | H_DIM,
                                               // so a band never crosses images)

    const float4* __restrict__ x4 = (const float4*)x;
    const int v0 = rowg0 * W4 + col4;          // float4 index of row 0

    // clamped window-edge row addresses (block-uniform branches)
    const int vup = (row0 == 0)            ? v0                  : v0 - W4;
    const int vdn = (row0 + RPT == H_DIM)  ? v0 + (RPT - 1) * W4 : v0 + RPT * W4;

    // ---- issue ALL 10 row loads before any use: 10 loads in flight ----
    float4 win[RPT + 2];                       // statically indexed after unroll
    #pragma unroll
    for (int r = 0; r < RPT; ++r)
        win[r + 1] = x4[v0 + r * W4];
    win[0]       = x4[vup];
    win[RPT + 1] = x4[vdn];

    // broadcast scalars (uniform addresses -> s_load, cached)
    const float a0 = a[0], a1 = a[1], a2 = a[2];
    const float w0 = w[0], w1 = w[1], w2 = w[2], w3 = w[3];

    #pragma unroll
    for (int r = 0; r < RPT; ++r) {
        const float4 up  = win[r];
        const float4 cur = win[r + 1];
        const float4 dn  = win[r + 2];

        // horizontal neighbors: adjacent lane's register via shuffle
        float lw = __shfl(cur.w, (lane > 0)  ? lane - 1 : 0);
        float rw = __shfl(cur.x, (lane < 63) ? lane + 1 : 63);
        // wave-edge lanes: 1-active-lane predicated scalar loads (L1/L2 hit)
        if (lane == 0)
            lw = (col4 == 0)      ? cur.x : x[(size_t)(v0 + r * W4) * 4 - 1];
        if (lane == 63)
            rw = (col4 == W4 - 1) ? cur.w : x[(size_t)(v0 + r * W4) * 4 + 4];

        fvec4 res;
        res.x = a0 * cur.x + a1 * (lw    + cur.y) + a2 * (up.x + dn.x)
              + fmaf(fmaf(fmaf(w3, cur.x, w2), cur.x, w1), cur.x, w0);
        res.y = a0 * cur.y + a1 * (cur.x + cur.z) + a2 * (up.y + dn.y)
              + fmaf(fmaf(fmaf(w3, cur.y, w2), cur.y, w1), cur.y, w0);
        res.z = a0 * cur.z + a1 * (cur.y + cur.w) + a2 * (up.z + dn.z)
              + fmaf(fmaf(fmaf(w3, cur.z, w2), cur.z, w1), cur.z, w0);
        res.w = a0 * cur.w + a1 * (cur.z + rw   ) + a2 * (up.w + dn.w)
              + fmaf(fmaf(fmaf(w3, cur.w, w2), cur.w, w1), cur.w, w0);

        // output never re-read: bypass cache retention
        __builtin_nontemporal_store(res, (fvec4*)(out + (size_t)(v0 + r * W4) * 4));
    }
}

extern "C" void kernel_launch(void* const* d_in, const int* in_sizes, int n_in,
                              void* d_out, int out_size, void* d_ws, size_t ws_size,
                              hipStream_t stream) {
    const float* x = (const float*)d_in[0];   // 16*1*2048*2048 fp32
    const float* a = (const float*)d_in[1];   // 3 fp32
    const float* w = (const float*)d_in[2];   // 4 fp32
    float* out = (float*)d_out;

    const int total4 = out_size / 4;          // 16,777,216 float4s
    const int grid = total4 / (BLK * RPT);    // 8192 blocks

    FCNN_63651415326860_kernel<<<grid, BLK, 0, stream>>>(x, a, w, out);
}